// Round 2
// baseline (272.943 us; speedup 1.0000x reference)
//
#include <hip/hip_runtime.h>
#include <hip/hip_bf16.h>

// One block = one sudoku graph (81 nodes). All convs as bf16 MFMA.
// S = (A+I) is identical for every graph, deg==21 everywhere -> norm = 1/21.
// Runtime dtype detection: inputs/outputs may be fp32 or bf16 depending on
// harness mode; a pre-kernel sniffs x's bit patterns and writes a flag to ws.
typedef __attribute__((ext_vector_type(8))) short bf16x8;
typedef __attribute__((ext_vector_type(4))) float f32x4;

__device__ __forceinline__ unsigned short f2b(float f) {
    __hip_bfloat16 h = __float2bfloat16(f);
    return __builtin_bit_cast(unsigned short, h);
}
__device__ __forceinline__ float b2f(unsigned short u) {
    unsigned v = ((unsigned)u) << 16;
    return __builtin_bit_cast(float, v);
}
// load element idx as float, from either fp32 or bf16 buffer
__device__ __forceinline__ float ldf(const void* p, int idx, bool f32) {
    return f32 ? ((const float*)p)[idx] : b2f(((const unsigned short*)p)[idx]);
}
// load element idx as bf16 bits, from either fp32 or bf16 buffer
__device__ __forceinline__ unsigned short ldb(const void* p, int idx, bool f32) {
    return f32 ? f2b(((const float*)p)[idx]) : ((const unsigned short*)p)[idx];
}

__global__ void detect_dtype(const unsigned short* __restrict__ x, int* __restrict__ flag) {
    if (threadIdx.x == 0 && blockIdx.x == 0) {
        int wild = 0;
        for (int i = 0; i < 256; ++i) {
            unsigned e = (x[i] >> 7) & 0xFF;  // bf16 exponent field
            if (e != 0 && (e < 0x68 || e > 0x90)) ++wild;
        }
        // bf16 N(0,1) data: ~0 wild. fp32 data: even ushorts are mantissa bits -> ~100 wild.
        *flag = (wild > 32) ? 1 : 0;
    }
}

#define SAT_STRIDE 104   // [f][cell], 208B rows: 16B-aligned, 2-way banks
#define SH_STRIDE  136   // [node][f], 272B rows: 16B-aligned, 2-way banks

__global__ __launch_bounds__(256, 2) void sudoku_gnn(
    const void* __restrict__ x,
    const void* __restrict__ W1, const void* __restrict__ b1,
    const void* __restrict__ W2, const void* __restrict__ b2,
    const void* __restrict__ Wa, const void* __restrict__ ba,
    const void* __restrict__ Wc, const void* __restrict__ bc,
    const void* __restrict__ Wn, const void* __restrict__ bn,
    const void* __restrict__ Wt, const void* __restrict__ bt,
    void* __restrict__ out, int nB, const int* __restrict__ flag)
{
    __shared__ __attribute__((aligned(16))) unsigned short sAT[128 * SAT_STRIDE]; // t^T: [f][cell]
    __shared__ __attribute__((aligned(16))) unsigned short sH [96  * SH_STRIDE ]; // h:   [node][f]
    __shared__ float sPoolPart[256];
    __shared__ float sPool[128];

    const bool f32 = (*flag != 0);   // uniform
    const int tid  = threadIdx.x;
    const int wave = tid >> 6;
    const int lane = tid & 63;
    const int ln15 = lane & 15;
    const int q    = lane >> 4;
    const int k0   = q * 8;
    const int mtb  = (wave & 1) * 3;      // 3 m-tiles (rows mtb*16 .. mtb*16+47)
    const int fb   = (wave >> 1) * 64;    // feature half (4 n-tiles)
    const int g    = blockIdx.x;

    // ---------- one-time register fragments ----------
    // x A-frags (conv1, K=32 zero-padded past c=10)
    bf16x8 xf[3];
#pragma unroll
    for (int mt = 0; mt < 3; ++mt) {
        int node = (mtb + mt) * 16 + ln15;
        bf16x8 v;
#pragma unroll
        for (int jj = 0; jj < 8; ++jj) {
            int c = k0 + jj;
            unsigned short bits = 0;
            if (node < 81 && c < 10) bits = ldb(x, (g * 81 + node) * 10 + c, f32);
            v[jj] = (short)bits;
        }
        xf[mt] = v;
    }
    // W1 B-frags
    bf16x8 w1f[4];
#pragma unroll
    for (int nt = 0; nt < 4; ++nt) {
        int f = fb + nt * 16 + ln15;
        bf16x8 v;
#pragma unroll
        for (int jj = 0; jj < 8; ++jj) {
            int c = k0 + jj;
            v[jj] = (short)((c < 10) ? ldb(W1, c * 128 + f, f32) : (unsigned short)0);
        }
        w1f[nt] = v;
    }
    // W2 B-frags (K=128 -> 4 chunks)
    bf16x8 w2f[4][4];
#pragma unroll
    for (int kc = 0; kc < 4; ++kc)
#pragma unroll
        for (int nt = 0; nt < 4; ++nt) {
            int f = fb + nt * 16 + ln15;
            bf16x8 v;
#pragma unroll
            for (int jj = 0; jj < 8; ++jj) {
                int k = kc * 32 + k0 + jj;
                v[jj] = (short)ldb(W2, k * 128 + f, f32);
            }
            w2f[kc][nt] = v;
        }
    // S A-frags, computed arithmetically (0/1 in bf16). K=96 -> 3 chunks.
    bf16x8 sfr[3][3];
#pragma unroll
    for (int kc = 0; kc < 3; ++kc)
#pragma unroll
        for (int mt = 0; mt < 3; ++mt) {
            int node = (mtb + mt) * 16 + ln15;
            int ni = node / 9, nj = node % 9;
            bf16x8 v;
#pragma unroll
            for (int jj = 0; jj < 8; ++jj) {
                int cell = kc * 32 + k0 + jj;
                int ci = cell / 9, cj = cell % 9;
                bool adj = (node < 81) && (cell < 81) &&
                           ((ni == ci) || (nj == cj) ||
                            ((ni / 3 == ci / 3) && (nj / 3 == cj / 3)));
                v[jj] = adj ? (short)0x3F80 : (short)0;
            }
            sfr[kc][mt] = v;
        }

    // zero sH pad rows 81..95 (read as A-rows in conv2; never rewritten)
    for (int idx = tid; idx < 15 * SH_STRIDE; idx += 256) sH[81 * SH_STRIDE + idx] = 0;

    const f32x4 z4 = {0.f, 0.f, 0.f, 0.f};
    f32x4 acc[3][4];

    // ---------- S1: t1 = x @ W1  ->  sAT[f][cell] ----------
#pragma unroll
    for (int mt = 0; mt < 3; ++mt)
#pragma unroll
        for (int nt = 0; nt < 4; ++nt)
            acc[mt][nt] = __builtin_amdgcn_mfma_f32_16x16x32_bf16(xf[mt], w1f[nt], z4, 0, 0, 0);
#pragma unroll
    for (int mt = 0; mt < 3; ++mt)
#pragma unroll
        for (int nt = 0; nt < 4; ++nt) {
            int f = fb + nt * 16 + ln15;
            int nodeb = (mtb + mt) * 16 + q * 4;
#pragma unroll
            for (int r = 0; r < 4; ++r)
                sAT[f * SAT_STRIDE + nodeb + r] = f2b(acc[mt][nt][r]);
        }
    __syncthreads();

    // ---------- S2: h1 = relu(S @ t1 / 21 + b1)  ->  sH[node][f] ----------
#pragma unroll
    for (int mt = 0; mt < 3; ++mt)
#pragma unroll
        for (int nt = 0; nt < 4; ++nt) acc[mt][nt] = z4;
#pragma unroll
    for (int kc = 0; kc < 3; ++kc) {
        bf16x8 bt4[4];
#pragma unroll
        for (int nt = 0; nt < 4; ++nt)
            bt4[nt] = *(const bf16x8*)&sAT[(fb + nt * 16 + ln15) * SAT_STRIDE + kc * 32 + k0];
#pragma unroll
        for (int mt = 0; mt < 3; ++mt)
#pragma unroll
            for (int nt = 0; nt < 4; ++nt)
                acc[mt][nt] = __builtin_amdgcn_mfma_f32_16x16x32_bf16(sfr[kc][mt], bt4[nt], acc[mt][nt], 0, 0, 0);
    }
#pragma unroll
    for (int nt = 0; nt < 4; ++nt) {
        int f = fb + nt * 16 + ln15;
        float bv = ldf(b1, f, f32);
#pragma unroll
        for (int mt = 0; mt < 3; ++mt) {
            int nodeb = (mtb + mt) * 16 + q * 4;
#pragma unroll
            for (int r = 0; r < 4; ++r) {
                int node = nodeb + r;
                if (node < 81) {
                    float h = fmaxf(acc[mt][nt][r] * (1.0f / 21.0f) + bv, 0.0f);
                    sH[node * SH_STRIDE + f] = f2b(h);
                }
            }
        }
    }
    __syncthreads();

    // ---------- S3: t2 = h1 @ W2  ->  sAT[f][cell] ----------
#pragma unroll
    for (int mt = 0; mt < 3; ++mt)
#pragma unroll
        for (int nt = 0; nt < 4; ++nt) acc[mt][nt] = z4;
#pragma unroll
    for (int kc = 0; kc < 4; ++kc) {
        bf16x8 at3[3];
#pragma unroll
        for (int mt = 0; mt < 3; ++mt)
            at3[mt] = *(const bf16x8*)&sH[((mtb + mt) * 16 + ln15) * SH_STRIDE + kc * 32 + k0];
#pragma unroll
        for (int mt = 0; mt < 3; ++mt)
#pragma unroll
            for (int nt = 0; nt < 4; ++nt)
                acc[mt][nt] = __builtin_amdgcn_mfma_f32_16x16x32_bf16(at3[mt], w2f[kc][nt], acc[mt][nt], 0, 0, 0);
    }
    // all S2 reads of sAT finished before the previous barrier -> safe to overwrite
#pragma unroll
    for (int mt = 0; mt < 3; ++mt)
#pragma unroll
        for (int nt = 0; nt < 4; ++nt) {
            int f = fb + nt * 16 + ln15;
            int nodeb = (mtb + mt) * 16 + q * 4;
#pragma unroll
            for (int r = 0; r < 4; ++r)
                sAT[f * SAT_STRIDE + nodeb + r] = f2b(acc[mt][nt][r]);
        }
    __syncthreads();

    // ---------- S4: h2 = relu(S @ t2 / 21 + b2), fused mean-pool ----------
#pragma unroll
    for (int mt = 0; mt < 3; ++mt)
#pragma unroll
        for (int nt = 0; nt < 4; ++nt) acc[mt][nt] = z4;
#pragma unroll
    for (int kc = 0; kc < 3; ++kc) {
        bf16x8 bt4[4];
#pragma unroll
        for (int nt = 0; nt < 4; ++nt)
            bt4[nt] = *(const bf16x8*)&sAT[(fb + nt * 16 + ln15) * SAT_STRIDE + kc * 32 + k0];
#pragma unroll
        for (int mt = 0; mt < 3; ++mt)
#pragma unroll
            for (int nt = 0; nt < 4; ++nt)
                acc[mt][nt] = __builtin_amdgcn_mfma_f32_16x16x32_bf16(sfr[kc][mt], bt4[nt], acc[mt][nt], 0, 0, 0);
    }
#pragma unroll
    for (int nt = 0; nt < 4; ++nt) {
        int f = fb + nt * 16 + ln15;
        float bv = ldf(b2, f, f32);
        float p = 0.f;
#pragma unroll
        for (int mt = 0; mt < 3; ++mt) {
            int nodeb = (mtb + mt) * 16 + q * 4;
#pragma unroll
            for (int r = 0; r < 4; ++r) {
                int node = nodeb + r;
                if (node < 81)
                    p += fmaxf(acc[mt][nt][r] * (1.0f / 21.0f) + bv, 0.0f);
            }
        }
        // reduce over the 4 quads (lanes 16 apart) -> lanes 0..15 hold the sum
        p += __shfl_down(p, 32);
        p += __shfl_down(p, 16);
        if (lane < 16) sPoolPart[(wave & 1) * 128 + f] = p;
    }
    __syncthreads();
    if (tid < 128) sPool[tid] = (sPoolPart[tid] + sPoolPart[128 + tid]) / 81.0f;
    __syncthreads();

    // ---------- S5: four heads (104 outputs per graph) ----------
    if (tid < 104) {
        const void* W;
        const void* bb;
        int oo, dim;
        size_t off;
        int o = tid;
        if (o < 4)       { W = Wa; bb = ba; oo = o;      dim = 4;  off = (size_t)g * 4 + oo; }
        else if (o < 85) { W = Wc; bb = bc; oo = o - 4;  dim = 81; off = (size_t)nB * 4  + (size_t)g * 81 + oo; }
        else if (o < 94) { W = Wn; bb = bn; oo = o - 85; dim = 9;  off = (size_t)nB * 85 + (size_t)g * 9  + oo; }
        else             { W = Wt; bb = bt; oo = o - 94; dim = 10; off = (size_t)nB * 94 + (size_t)g * 10 + oo; }
        float a = ldf(bb, oo, f32);
#pragma unroll 8
        for (int f = 0; f < 128; ++f)
            a += sPool[f] * ldf(W, f * dim + oo, f32);
        if (f32) ((float*)out)[off] = a;
        else     ((unsigned short*)out)[off] = f2b(a);
    }
}

extern "C" void kernel_launch(void* const* d_in, const int* in_sizes, int n_in,
                              void* d_out, int out_size, void* d_ws, size_t ws_size,
                              hipStream_t stream) {
    // setup_inputs order: x, edge_index, batch, W1, b1, W2, b2, Wa, ba, Wc, bc, Wn, bn, Wt, bt
    const void* x  = d_in[0];
    const void* W1 = d_in[3];
    const void* b1 = d_in[4];
    const void* W2 = d_in[5];
    const void* b2 = d_in[6];
    const void* Wa = d_in[7];
    const void* ba = d_in[8];
    const void* Wc = d_in[9];
    const void* bc = d_in[10];
    const void* Wn = d_in[11];
    const void* bn = d_in[12];
    const void* Wt = d_in[13];
    const void* bt = d_in[14];

    int nB = in_sizes[2] / 81;   // batch array has B*81 entries
    if (nB <= 0) return;

    int* flag = (int*)d_ws;
    hipLaunchKernelGGL(detect_dtype, dim3(1), dim3(64), 0, stream,
                       (const unsigned short*)x, flag);
    hipLaunchKernelGGL(sudoku_gnn, dim3(nB), dim3(256), 0, stream,
                       x, W1, b1, W2, b2, Wa, ba, Wc, bc, Wn, bn, Wt, bt, d_out, nB, flag);
}

// Round 3
// 156.821 us; speedup vs baseline: 1.7405x; 1.7405x over previous
//
#include <hip/hip_runtime.h>
#include <hip/hip_bf16.h>

// One block = one sudoku graph (81 nodes). All convs as bf16 MFMA.
// S = (A+I) identical for every graph, deg==21 -> norm = 1/21.
// Block-invariant data (W1/W2/S fragments, head weights, biases) is repacked
// once into d_ws by a pre-kernel; main kernel does only vector loads.
typedef __attribute__((ext_vector_type(8))) short bf16x8;
typedef __attribute__((ext_vector_type(4))) float f32x4;

__device__ __forceinline__ unsigned short f2b(float f) {
    __hip_bfloat16 h = __float2bfloat16(f);
    return __builtin_bit_cast(unsigned short, h);
}
__device__ __forceinline__ float b2f(unsigned short u) {
    unsigned v = ((unsigned)u) << 16;
    return __builtin_bit_cast(float, v);
}
__device__ __forceinline__ float ldf(const void* p, int idx, bool f32) {
    return f32 ? ((const float*)p)[idx] : b2f(((const unsigned short*)p)[idx]);
}
__device__ __forceinline__ unsigned short ldb(const void* p, int idx, bool f32) {
    return f32 ? f2b(((const float*)p)[idx]) : ((const unsigned short*)p)[idx];
}

// ---- ws layout (bytes) ----
#define WS_FLAG   0
#define WS_B1F    16        // 128 f32
#define WS_B2F    528       // 128 f32
#define WS_BHF    1040      // 104 f32
#define WS_W1R    1536      // 128*32 bf16   [f][k]
#define WS_W2R    9728      // 128*128 bf16  [f][k]
#define WS_SR     42496     // 18*64*8 bf16  [(mi*3+kc)*64+lane][j]
#define WS_WH     60928     // 104*128 f32   [o][f]

// ---------------- dtype detection (parallel) ----------------
__global__ void k_detect(const unsigned short* __restrict__ x, int* __restrict__ flag) {
    int lane = threadIdx.x;   // 64 threads
    int wild = 0;
#pragma unroll
    for (int i = 0; i < 4; ++i) {
        unsigned e = (x[lane * 4 + i] >> 7) & 0xFF;  // bf16 exponent field
        if (e != 0 && (e < 0x68 || e > 0x90)) ++wild;
    }
#pragma unroll
    for (int off = 32; off; off >>= 1) wild += __shfl_down(wild, off);
    if (lane == 0) *flag = (wild > 32) ? 1 : 0;  // fp32 data -> ~100 wild
}

// ---------------- block-invariant repack ----------------
__global__ void k_repack(const void* __restrict__ W1, const void* __restrict__ b1,
                         const void* __restrict__ W2, const void* __restrict__ b2,
                         const void* __restrict__ Wa, const void* __restrict__ ba,
                         const void* __restrict__ Wc, const void* __restrict__ bc,
                         const void* __restrict__ Wn, const void* __restrict__ bn,
                         const void* __restrict__ Wt, const void* __restrict__ bt,
                         char* __restrict__ ws) {
    const bool f32 = (*(const int*)(ws + WS_FLAG)) != 0;
    int idx = blockIdx.x * blockDim.x + threadIdx.x;
    // T0: w1r 4096
    if (idx < 4096) {
        int f = idx >> 5, k = idx & 31;
        unsigned short v = (k < 10) ? ldb(W1, k * 128 + f, f32) : (unsigned short)0;
        ((unsigned short*)(ws + WS_W1R))[idx] = v;
        return;
    }
    idx -= 4096;
    // T1: w2r 16384
    if (idx < 16384) {
        int f = idx >> 7, k = idx & 127;
        ((unsigned short*)(ws + WS_W2R))[idx] = ldb(W2, k * 128 + f, f32);
        return;
    }
    idx -= 16384;
    // T2: sr 9216
    if (idx < 9216) {
        int fi = idx >> 9, rem = idx & 511;
        int lane = rem >> 3, j = rem & 7;
        int mi = fi / 3, kc = fi - mi * 3;
        int node = mi * 16 + (lane & 15);
        int cell = kc * 32 + ((lane >> 4) << 3) + j;
        bool adj = false;
        if (node < 81 && cell < 81) {
            int ni = node / 9, nj = node % 9;
            int ci = cell / 9, cj = cell % 9;
            adj = (ni == ci) || (nj == cj) ||
                  ((ni / 3 == ci / 3) && (nj / 3 == cj / 3));
        }
        ((unsigned short*)(ws + WS_SR))[idx] = adj ? (unsigned short)0x3F80 : (unsigned short)0;
        return;
    }
    idx -= 9216;
    // T3: head weights 13312 (f32, exact in both modes)
    if (idx < 13312) {
        int o = idx >> 7, f = idx & 127;
        const void* W; int oo, dim;
        if (o < 4)       { W = Wa; oo = o;      dim = 4;  }
        else if (o < 85) { W = Wc; oo = o - 4;  dim = 81; }
        else if (o < 94) { W = Wn; oo = o - 85; dim = 9;  }
        else             { W = Wt; oo = o - 94; dim = 10; }
        ((float*)(ws + WS_WH))[idx] = ldf(W, f * dim + oo, f32);
        return;
    }
    idx -= 13312;
    // T4: biases 360
    if (idx < 360) {
        float v;
        if (idx < 128)      v = ldf(b1, idx, f32);
        else if (idx < 256) v = ldf(b2, idx - 128, f32);
        else {
            int o = idx - 256;
            if (o < 4)       v = ldf(ba, o, f32);
            else if (o < 85) v = ldf(bc, o - 4, f32);
            else if (o < 94) v = ldf(bn, o - 85, f32);
            else             v = ldf(bt, o - 94, f32);
        }
        if (idx < 128)      ((float*)(ws + WS_B1F))[idx] = v;
        else if (idx < 256) ((float*)(ws + WS_B2F))[idx - 128] = v;
        else                ((float*)(ws + WS_BHF))[idx - 256] = v;
    }
}

#define SAT_STRIDE 104   // [f][cell], 208B rows: 16B-aligned, 2-way banks (free)
#define SH_STRIDE  136   // [node][f], 272B rows: 16B-aligned, 2-way banks (free)

__global__ __launch_bounds__(256, 2) void sudoku_gnn(
    const void* __restrict__ x, const char* __restrict__ ws,
    void* __restrict__ out, int nB)
{
    __shared__ __attribute__((aligned(16))) unsigned short sAT[128 * SAT_STRIDE]; // t^T: [f][cell]
    __shared__ __attribute__((aligned(16))) unsigned short sH [96  * SH_STRIDE ]; // h:   [node][f]
    __shared__ __attribute__((aligned(16))) unsigned int   xs[816];               // raw x stage
    __shared__ float sPoolPart[256];
    __shared__ float sPool[128];

    const bool f32 = (*(const int*)(ws + WS_FLAG)) != 0;   // uniform
    const unsigned short* w1r = (const unsigned short*)(ws + WS_W1R);
    const unsigned short* w2r = (const unsigned short*)(ws + WS_W2R);
    const unsigned short* sr  = (const unsigned short*)(ws + WS_SR);
    const float* b1f = (const float*)(ws + WS_B1F);
    const float* b2f = (const float*)(ws + WS_B2F);
    const float* bhf = (const float*)(ws + WS_BHF);
    const float* whf = (const float*)(ws + WS_WH);

    const int tid  = threadIdx.x;
    const int wave = tid >> 6;
    const int lane = tid & 63;
    const int ln15 = lane & 15;
    const int q    = lane >> 4;
    const int k0   = q * 8;
    const int mtb  = (wave & 1) * 3;      // row tiles mtb..mtb+2 (16 rows each)
    const int fb   = (wave >> 1) * 64;    // feature half (4 n-tiles)
    const int g    = blockIdx.x;

    // ---- stage raw x bytes for this graph into LDS (dtype-agnostic) ----
    {
        const int words = f32 ? 810 : 405;        // 81*10 elems
        const unsigned int* src = (const unsigned int*)x + (size_t)g * words;
        for (int i = tid; i < words; i += 256) xs[i] = src[i];
    }

    // ---- persistent fragments: S (A-op), from ws (coalesced 16B loads) ----
    bf16x8 sfr[3][3];
#pragma unroll
    for (int kc = 0; kc < 3; ++kc)
#pragma unroll
        for (int mt = 0; mt < 3; ++mt) {
            int mi = mtb + mt;
            sfr[kc][mt] = *(const bf16x8*)&sr[((mi * 3 + kc) * 64 + lane) * 8];
        }
    // W1 B-frags from ws
    bf16x8 w1f[4];
#pragma unroll
    for (int nt = 0; nt < 4; ++nt) {
        int f = fb + nt * 16 + ln15;
        w1f[nt] = *(const bf16x8*)&w1r[f * 32 + k0];
    }

    // zero sH pad rows 81..95
    for (int idx = tid; idx < 15 * SH_STRIDE; idx += 256) sH[81 * SH_STRIDE + idx] = 0;
    __syncthreads();   // xs ready

    // ---- x A-frags from LDS stage ----
    bf16x8 xf[3];
#pragma unroll
    for (int mt = 0; mt < 3; ++mt) {
        int node = (mtb + mt) * 16 + ln15;
        bf16x8 v = {0, 0, 0, 0, 0, 0, 0, 0};
        if (node < 81) {
            if (q == 0) {
#pragma unroll
                for (int jj = 0; jj < 8; ++jj)
                    v[jj] = (short)(f32 ? f2b(((const float*)xs)[node * 10 + jj])
                                        : ((const unsigned short*)xs)[node * 10 + jj]);
            } else if (q == 1) {
#pragma unroll
                for (int jj = 0; jj < 2; ++jj)
                    v[jj] = (short)(f32 ? f2b(((const float*)xs)[node * 10 + 8 + jj])
                                        : ((const unsigned short*)xs)[node * 10 + 8 + jj]);
            }
        }
        xf[mt] = v;
    }

    const f32x4 z4 = {0.f, 0.f, 0.f, 0.f};
    f32x4 acc[3][4];

    // ---------- S1: t1 = x @ W1  ->  sAT[f][cell] ----------
#pragma unroll
    for (int mt = 0; mt < 3; ++mt)
#pragma unroll
        for (int nt = 0; nt < 4; ++nt)
            acc[mt][nt] = __builtin_amdgcn_mfma_f32_16x16x32_bf16(xf[mt], w1f[nt], z4, 0, 0, 0);
#pragma unroll
    for (int mt = 0; mt < 3; ++mt)
#pragma unroll
        for (int nt = 0; nt < 4; ++nt) {
            int f = fb + nt * 16 + ln15;
            int nodeb = (mtb + mt) * 16 + q * 4;
            unsigned lo = (unsigned)f2b(acc[mt][nt][0]) | ((unsigned)f2b(acc[mt][nt][1]) << 16);
            unsigned hi = (unsigned)f2b(acc[mt][nt][2]) | ((unsigned)f2b(acc[mt][nt][3]) << 16);
            *(uint2*)&sAT[f * SAT_STRIDE + nodeb] = make_uint2(lo, hi);
        }
    __syncthreads();

    // ---------- S2: h1 = relu(S @ t1 / 21 + b1)  ->  sH[node][f] ----------
#pragma unroll
    for (int mt = 0; mt < 3; ++mt)
#pragma unroll
        for (int nt = 0; nt < 4; ++nt) acc[mt][nt] = z4;
#pragma unroll
    for (int kc = 0; kc < 3; ++kc) {
        bf16x8 bt4[4];
#pragma unroll
        for (int nt = 0; nt < 4; ++nt)
            bt4[nt] = *(const bf16x8*)&sAT[(fb + nt * 16 + ln15) * SAT_STRIDE + kc * 32 + k0];
#pragma unroll
        for (int mt = 0; mt < 3; ++mt)
#pragma unroll
            for (int nt = 0; nt < 4; ++nt)
                acc[mt][nt] = __builtin_amdgcn_mfma_f32_16x16x32_bf16(sfr[kc][mt], bt4[nt], acc[mt][nt], 0, 0, 0);
    }
#pragma unroll
    for (int nt = 0; nt < 4; ++nt) {
        int f = fb + nt * 16 + ln15;
        float bv = b1f[f];
#pragma unroll
        for (int mt = 0; mt < 3; ++mt) {
            int nodeb = (mtb + mt) * 16 + q * 4;
#pragma unroll
            for (int r = 0; r < 4; ++r) {
                int node = nodeb + r;
                if (node < 81) {
                    float h = fmaxf(acc[mt][nt][r] * (1.0f / 21.0f) + bv, 0.0f);
                    sH[node * SH_STRIDE + f] = f2b(h);
                }
            }
        }
    }
    __syncthreads();

    // ---------- S3: t2 = h1 @ W2  ->  sAT[f][cell] ----------
#pragma unroll
    for (int mt = 0; mt < 3; ++mt)
#pragma unroll
        for (int nt = 0; nt < 4; ++nt) acc[mt][nt] = z4;
#pragma unroll
    for (int kc = 0; kc < 4; ++kc) {
        bf16x8 w2f[4];
#pragma unroll
        for (int nt = 0; nt < 4; ++nt)
            w2f[nt] = *(const bf16x8*)&w2r[(fb + nt * 16 + ln15) * 128 + kc * 32 + k0];
        bf16x8 at3[3];
#pragma unroll
        for (int mt = 0; mt < 3; ++mt)
            at3[mt] = *(const bf16x8*)&sH[((mtb + mt) * 16 + ln15) * SH_STRIDE + kc * 32 + k0];
#pragma unroll
        for (int mt = 0; mt < 3; ++mt)
#pragma unroll
            for (int nt = 0; nt < 4; ++nt)
                acc[mt][nt] = __builtin_amdgcn_mfma_f32_16x16x32_bf16(at3[mt], w2f[nt], acc[mt][nt], 0, 0, 0);
    }
#pragma unroll
    for (int mt = 0; mt < 3; ++mt)
#pragma unroll
        for (int nt = 0; nt < 4; ++nt) {
            int f = fb + nt * 16 + ln15;
            int nodeb = (mtb + mt) * 16 + q * 4;
            unsigned lo = (unsigned)f2b(acc[mt][nt][0]) | ((unsigned)f2b(acc[mt][nt][1]) << 16);
            unsigned hi = (unsigned)f2b(acc[mt][nt][2]) | ((unsigned)f2b(acc[mt][nt][3]) << 16);
            *(uint2*)&sAT[f * SAT_STRIDE + nodeb] = make_uint2(lo, hi);
        }
    __syncthreads();

    // ---------- S4: h2 = relu(S @ t2 / 21 + b2), fused mean-pool ----------
#pragma unroll
    for (int mt = 0; mt < 3; ++mt)
#pragma unroll
        for (int nt = 0; nt < 4; ++nt) acc[mt][nt] = z4;
#pragma unroll
    for (int kc = 0; kc < 3; ++kc) {
        bf16x8 bt4[4];
#pragma unroll
        for (int nt = 0; nt < 4; ++nt)
            bt4[nt] = *(const bf16x8*)&sAT[(fb + nt * 16 + ln15) * SAT_STRIDE + kc * 32 + k0];
#pragma unroll
        for (int mt = 0; mt < 3; ++mt)
#pragma unroll
            for (int nt = 0; nt < 4; ++nt)
                acc[mt][nt] = __builtin_amdgcn_mfma_f32_16x16x32_bf16(sfr[kc][mt], bt4[nt], acc[mt][nt], 0, 0, 0);
    }
#pragma unroll
    for (int nt = 0; nt < 4; ++nt) {
        int f = fb + nt * 16 + ln15;
        float bv = b2f[f];
        float p = 0.f;
#pragma unroll
        for (int mt = 0; mt < 3; ++mt) {
            int nodeb = (mtb + mt) * 16 + q * 4;
#pragma unroll
            for (int r = 0; r < 4; ++r) {
                int node = nodeb + r;
                if (node < 81)
                    p += fmaxf(acc[mt][nt][r] * (1.0f / 21.0f) + bv, 0.0f);
            }
        }
        p += __shfl_down(p, 32);
        p += __shfl_down(p, 16);
        if (lane < 16) sPoolPart[(wave & 1) * 128 + f] = p;
    }
    __syncthreads();
    if (tid < 128) sPool[tid] = (sPoolPart[tid] + sPoolPart[128 + tid]) / 81.0f;
    __syncthreads();

    // ---------- S5: four heads (104 outputs) ----------
    if (tid < 104) {
        float a = bhf[tid];
        const float4* wrow = (const float4*)(whf + tid * 128);
#pragma unroll 8
        for (int i = 0; i < 32; ++i) {
            float4 wv = wrow[i];
            a += sPool[i * 4 + 0] * wv.x + sPool[i * 4 + 1] * wv.y +
                 sPool[i * 4 + 2] * wv.z + sPool[i * 4 + 3] * wv.w;
        }
        int o = tid, oo; size_t off;
        if (o < 4)       { oo = o;      off = (size_t)g * 4 + oo; }
        else if (o < 85) { oo = o - 4;  off = (size_t)nB * 4  + (size_t)g * 81 + oo; }
        else if (o < 94) { oo = o - 85; off = (size_t)nB * 85 + (size_t)g * 9  + oo; }
        else             { oo = o - 94; off = (size_t)nB * 94 + (size_t)g * 10 + oo; }
        if (f32) ((float*)out)[off] = a;
        else     ((unsigned short*)out)[off] = f2b(a);
    }
}

extern "C" void kernel_launch(void* const* d_in, const int* in_sizes, int n_in,
                              void* d_out, int out_size, void* d_ws, size_t ws_size,
                              hipStream_t stream) {
    // setup_inputs order: x, edge_index, batch, W1, b1, W2, b2, Wa, ba, Wc, bc, Wn, bn, Wt, bt
    const void* x  = d_in[0];
    int nB = in_sizes[2] / 81;
    if (nB <= 0) return;

    char* ws = (char*)d_ws;
    hipLaunchKernelGGL(k_detect, dim3(1), dim3(64), 0, stream,
                       (const unsigned short*)x, (int*)(ws + WS_FLAG));
    hipLaunchKernelGGL(k_repack, dim3(170), dim3(256), 0, stream,
                       d_in[3], d_in[4], d_in[5], d_in[6],
                       d_in[7], d_in[8], d_in[9], d_in[10],
                       d_in[11], d_in[12], d_in[13], d_in[14], ws);
    hipLaunchKernelGGL(sudoku_gnn, dim3(nB), dim3(256), 0, stream,
                       x, (const char*)ws, d_out, nB);
}

// Round 4
// 147.567 us; speedup vs baseline: 1.8496x; 1.0627x over previous
//
#include <hip/hip_runtime.h>
#include <hip/hip_bf16.h>

// One block = one sudoku graph (81 nodes, padded to 96). All matmuls bf16 MFMA.
// S = (A+I) identical for every graph, symmetric, deg==21 -> norm = 1/21.
// Transposed-aggregation trick: computing h^T = t^T @ S (S symmetric) makes every
// MFMA C-tile write land as 4 consecutive elements per lane (b64, conflict-free)
// in exactly the layout the next phase consumes -> single aliased LDS buffer.
typedef __attribute__((ext_vector_type(8))) short bf16x8;
typedef __attribute__((ext_vector_type(4))) float f32x4;

__device__ __forceinline__ unsigned short f2b(float f) {
    __hip_bfloat16 h = __float2bfloat16(f);
    return __builtin_bit_cast(unsigned short, h);
}
__device__ __forceinline__ float b2f(unsigned short u) {
    unsigned v = ((unsigned)u) << 16;
    return __builtin_bit_cast(float, v);
}
__device__ __forceinline__ float ldf(const void* p, int idx, bool f32) {
    return f32 ? ((const float*)p)[idx] : b2f(((const unsigned short*)p)[idx]);
}
__device__ __forceinline__ unsigned short ldb(const void* p, int idx, bool f32) {
    return f32 ? f2b(((const float*)p)[idx]) : ((const unsigned short*)p)[idx];
}

// dtype sniff from a uniform 64B of x: even-index ushorts of fp32 data are
// mantissa bits -> "wild" bf16 exponents w.p. ~0.84; bf16 N(0,1) data ~never.
// 16 samples, threshold 8: error prob ~1e-13 per call.
__device__ __forceinline__ bool sniff_f32(const void* x) {
    const unsigned* p = (const unsigned*)x;
    int wild = 0;
#pragma unroll
    for (int i = 0; i < 16; ++i) {
        unsigned e = (p[i] >> 7) & 0xFF;  // exponent field of even-index ushort
        wild += (e != 0 && (e < 0x68 || e > 0x90)) ? 1 : 0;
    }
    return wild > 8;
}

// ---- ws layout (bytes) ----
#define WS_B1F    16        // 128 f32
#define WS_B2F    528       // 128 f32
#define WS_BHF    1040      // 104 f32
#define WS_W1R    1536      // 128*32 bf16   [f][k]
#define WS_W2R    9728      // 128*128 bf16  [f][k]
#define WS_SR     42496     // 18*64*8 bf16  [(mi*3+kc)*64+lane][j]
#define WS_WH     60928     // 104*128 f32   [o][f]

// ---------------- block-invariant repack ----------------
__global__ void k_repack(const void* __restrict__ x,
                         const void* __restrict__ W1, const void* __restrict__ b1,
                         const void* __restrict__ W2, const void* __restrict__ b2,
                         const void* __restrict__ Wa, const void* __restrict__ ba,
                         const void* __restrict__ Wc, const void* __restrict__ bc,
                         const void* __restrict__ Wn, const void* __restrict__ bn,
                         const void* __restrict__ Wt, const void* __restrict__ bt,
                         char* __restrict__ ws) {
    const bool f32 = sniff_f32(x);
    int idx = blockIdx.x * blockDim.x + threadIdx.x;
    if (idx < 4096) {                         // w1r
        int f = idx >> 5, k = idx & 31;
        unsigned short v = (k < 10) ? ldb(W1, k * 128 + f, f32) : (unsigned short)0;
        ((unsigned short*)(ws + WS_W1R))[idx] = v;
        return;
    }
    idx -= 4096;
    if (idx < 16384) {                        // w2r
        int f = idx >> 7, k = idx & 127;
        ((unsigned short*)(ws + WS_W2R))[idx] = ldb(W2, k * 128 + f, f32);
        return;
    }
    idx -= 16384;
    if (idx < 9216) {                         // S fragments
        int fi = idx >> 9, rem = idx & 511;
        int lane = rem >> 3, j = rem & 7;
        int mi = fi / 3, kc = fi - mi * 3;
        int node = mi * 16 + (lane & 15);
        int cell = kc * 32 + ((lane >> 4) << 3) + j;
        bool adj = false;
        if (node < 81 && cell < 81) {
            int ni = node / 9, nj = node % 9;
            int ci = cell / 9, cj = cell % 9;
            adj = (ni == ci) || (nj == cj) ||
                  ((ni / 3 == ci / 3) && (nj / 3 == cj / 3));
        }
        ((unsigned short*)(ws + WS_SR))[idx] = adj ? (unsigned short)0x3F80 : (unsigned short)0;
        return;
    }
    idx -= 9216;
    if (idx < 13312) {                        // head weights (f32)
        int o = idx >> 7, f = idx & 127;
        const void* W; int oo, dim;
        if (o < 4)       { W = Wa; oo = o;      dim = 4;  }
        else if (o < 85) { W = Wc; oo = o - 4;  dim = 81; }
        else if (o < 94) { W = Wn; oo = o - 85; dim = 9;  }
        else             { W = Wt; oo = o - 94; dim = 10; }
        ((float*)(ws + WS_WH))[idx] = ldf(W, f * dim + oo, f32);
        return;
    }
    idx -= 13312;
    if (idx < 360) {                          // biases
        float v;
        if (idx < 128)      v = ldf(b1, idx, f32);
        else if (idx < 256) v = ldf(b2, idx - 128, f32);
        else {
            int o = idx - 256;
            if (o < 4)       v = ldf(ba, o, f32);
            else if (o < 85) v = ldf(bc, o - 4, f32);
            else if (o < 94) v = ldf(bn, o - 85, f32);
            else             v = ldf(bt, o - 94, f32);
        }
        if (idx < 128)      ((float*)(ws + WS_B1F))[idx] = v;
        else if (idx < 256) ((float*)(ws + WS_B2F))[idx - 128] = v;
        else                ((float*)(ws + WS_BHF))[idx - 256] = v;
    }
}

#define T_STRIDE 104   // t^T view: [f:128][cell], rows 208B (16B-aligned)
#define H_STRIDE 136   // h view:   [node:96][f],  rows 272B (16B-aligned)

__global__ __launch_bounds__(256, 4) void sudoku_gnn(
    const void* __restrict__ x, const char* __restrict__ ws,
    void* __restrict__ out, int nB)
{
    __shared__ __attribute__((aligned(16))) unsigned short sBuf[13312]; // aliased t^T / h
    __shared__ __attribute__((aligned(16))) unsigned int   xs[816];     // raw x stage
    __shared__ float sPoolPart[256];
    __shared__ float sPool[128];

    const bool f32 = sniff_f32(x);   // uniform (scalar loads)
    const unsigned short* w1r = (const unsigned short*)(ws + WS_W1R);
    const unsigned short* w2r = (const unsigned short*)(ws + WS_W2R);
    const unsigned short* sr  = (const unsigned short*)(ws + WS_SR);
    const float* b1f = (const float*)(ws + WS_B1F);
    const float* b2f = (const float*)(ws + WS_B2F);
    const float* bhf = (const float*)(ws + WS_BHF);
    const float* whf = (const float*)(ws + WS_WH);

    const int tid  = threadIdx.x;
    const int wave = tid >> 6;
    const int lane = tid & 63;
    const int ln15 = lane & 15;
    const int q    = lane >> 4;
    const int k0   = q * 8;
    const int mtb  = (wave & 1) * 3;      // node-half: tiles mtb..mtb+2
    const int nb   = (wave & 1) * 48;     // node-half base
    const int fb   = (wave >> 1) * 64;    // feature half
    const int g    = blockIdx.x;
    const float inv21 = 1.0f / 21.0f;

    // ---- stage raw x for this graph into LDS (dtype-agnostic words) ----
    {
        const int words = f32 ? 810 : 405;
        const unsigned int* src = (const unsigned int*)x + (size_t)g * words;
        for (int i = tid; i < words; i += 256) xs[i] = src[i];
    }

    // ---- persistent S fragments (A/B interchangeable: S symmetric) ----
    bf16x8 sfr[3][3];
#pragma unroll
    for (int kc = 0; kc < 3; ++kc)
#pragma unroll
        for (int jt = 0; jt < 3; ++jt)
            sfr[kc][jt] = *(const bf16x8*)&sr[(((mtb + jt) * 3 + kc) * 64 + lane) * 8];
    // W1 B-frags
    bf16x8 w1f[4];
#pragma unroll
    for (int nt = 0; nt < 4; ++nt)
        w1f[nt] = *(const bf16x8*)&w1r[(fb + nt * 16 + ln15) * 32 + k0];

    __syncthreads();   // xs ready

    // ---- x A-frags from LDS ----
    bf16x8 xf[3];
#pragma unroll
    for (int mt = 0; mt < 3; ++mt) {
        int node = (mtb + mt) * 16 + ln15;
        bf16x8 v = {0, 0, 0, 0, 0, 0, 0, 0};
        if (node < 81) {
            if (q == 0) {
#pragma unroll
                for (int jj = 0; jj < 8; ++jj)
                    v[jj] = (short)(f32 ? f2b(((const float*)xs)[node * 10 + jj])
                                        : ((const unsigned short*)xs)[node * 10 + jj]);
            } else if (q == 1) {
#pragma unroll
                for (int jj = 0; jj < 2; ++jj)
                    v[jj] = (short)(f32 ? f2b(((const float*)xs)[node * 10 + 8 + jj])
                                        : ((const unsigned short*)xs)[node * 10 + 8 + jj]);
            }
        }
        xf[mt] = v;
    }

    const f32x4 z4 = {0.f, 0.f, 0.f, 0.f};
    f32x4 acc[3][4];   // reused by every phase (one live at a time)

    // ---------- S1: t1 = x @ W1 ; C[m=node][n=f] -> write t1^T[f][cell] ----------
#pragma unroll
    for (int mt = 0; mt < 3; ++mt)
#pragma unroll
        for (int nt = 0; nt < 4; ++nt)
            acc[mt][nt] = __builtin_amdgcn_mfma_f32_16x16x32_bf16(xf[mt], w1f[nt], z4, 0, 0, 0);
#pragma unroll
    for (int mt = 0; mt < 3; ++mt)
#pragma unroll
        for (int nt = 0; nt < 4; ++nt) {
            int f = fb + nt * 16 + ln15;
            int nodeb = (mtb + mt) * 16 + q * 4;
            unsigned lo = (unsigned)f2b(acc[mt][nt][0]) | ((unsigned)f2b(acc[mt][nt][1]) << 16);
            unsigned hi = (unsigned)f2b(acc[mt][nt][2]) | ((unsigned)f2b(acc[mt][nt][3]) << 16);
            *(uint2*)&sBuf[f * T_STRIDE + nodeb] = make_uint2(lo, hi);
        }
    __syncthreads();

    // ---------- S2: h1^T = t1^T @ S ; C[m=f][n=node] -> write h1[node][f] ----------
#pragma unroll
    for (int at = 0; at < 3; ++at)
#pragma unroll
        for (int jt = 0; jt < 4; ++jt) acc[at][jt] = z4;   // [jt<3 used]
#pragma unroll
    for (int kc = 0; kc < 3; ++kc) {
        bf16x8 a4[4];
#pragma unroll
        for (int at = 0; at < 4; ++at)
            a4[at] = *(const bf16x8*)&sBuf[(fb + at * 16 + ln15) * T_STRIDE + kc * 32 + k0];
#pragma unroll
        for (int at = 0; at < 4; ++at)
#pragma unroll
            for (int jt = 0; jt < 3; ++jt)
                acc[jt][at] = __builtin_amdgcn_mfma_f32_16x16x32_bf16(a4[at], sfr[kc][jt], acc[jt][at], 0, 0, 0);
    }
    __syncthreads();   // all reads of t1^T complete before aliased writes
#pragma unroll
    for (int at = 0; at < 4; ++at) {
        float4 bv = *(const float4*)&b1f[fb + at * 16 + q * 4];
#pragma unroll
        for (int jt = 0; jt < 3; ++jt) {
            int node = nb + jt * 16 + ln15;
            float v0 = fmaxf(acc[jt][at][0] * inv21 + bv.x, 0.0f);
            float v1 = fmaxf(acc[jt][at][1] * inv21 + bv.y, 0.0f);
            float v2 = fmaxf(acc[jt][at][2] * inv21 + bv.z, 0.0f);
            float v3 = fmaxf(acc[jt][at][3] * inv21 + bv.w, 0.0f);
            unsigned lo = (unsigned)f2b(v0) | ((unsigned)f2b(v1) << 16);
            unsigned hi = (unsigned)f2b(v2) | ((unsigned)f2b(v3) << 16);
            *(uint2*)&sBuf[node * H_STRIDE + fb + at * 16 + q * 4] = make_uint2(lo, hi);
        }
    }
    __syncthreads();

    // ---------- S3: t2 = h1 @ W2 ; C[m=node][n=f] -> write t2^T[f][cell] ----------
#pragma unroll
    for (int mt = 0; mt < 3; ++mt)
#pragma unroll
        for (int nt = 0; nt < 4; ++nt) acc[mt][nt] = z4;
#pragma unroll
    for (int kc = 0; kc < 4; ++kc) {
        bf16x8 w2f[4];
#pragma unroll
        for (int nt = 0; nt < 4; ++nt)
            w2f[nt] = *(const bf16x8*)&w2r[(fb + nt * 16 + ln15) * 128 + kc * 32 + k0];
        bf16x8 a3[3];
#pragma unroll
        for (int mt = 0; mt < 3; ++mt)
            a3[mt] = *(const bf16x8*)&sBuf[((mtb + mt) * 16 + ln15) * H_STRIDE + kc * 32 + k0];
#pragma unroll
        for (int mt = 0; mt < 3; ++mt)
#pragma unroll
            for (int nt = 0; nt < 4; ++nt)
                acc[mt][nt] = __builtin_amdgcn_mfma_f32_16x16x32_bf16(a3[mt], w2f[nt], acc[mt][nt], 0, 0, 0);
    }
    __syncthreads();   // all reads of h1 complete before aliased writes
#pragma unroll
    for (int mt = 0; mt < 3; ++mt)
#pragma unroll
        for (int nt = 0; nt < 4; ++nt) {
            int f = fb + nt * 16 + ln15;
            int nodeb = (mtb + mt) * 16 + q * 4;
            unsigned lo = (unsigned)f2b(acc[mt][nt][0]) | ((unsigned)f2b(acc[mt][nt][1]) << 16);
            unsigned hi = (unsigned)f2b(acc[mt][nt][2]) | ((unsigned)f2b(acc[mt][nt][3]) << 16);
            *(uint2*)&sBuf[f * T_STRIDE + nodeb] = make_uint2(lo, hi);
        }
    __syncthreads();

    // ---------- S4: h2^T = t2^T @ S ; relu(+b2), fused mean-pool over nodes ----------
#pragma unroll
    for (int at = 0; at < 3; ++at)
#pragma unroll
        for (int jt = 0; jt < 4; ++jt) acc[at][jt] = z4;
#pragma unroll
    for (int kc = 0; kc < 3; ++kc) {
        bf16x8 a4[4];
#pragma unroll
        for (int at = 0; at < 4; ++at)
            a4[at] = *(const bf16x8*)&sBuf[(fb + at * 16 + ln15) * T_STRIDE + kc * 32 + k0];
#pragma unroll
        for (int at = 0; at < 4; ++at)
#pragma unroll
            for (int jt = 0; jt < 3; ++jt)
                acc[jt][at] = __builtin_amdgcn_mfma_f32_16x16x32_bf16(a4[at], sfr[kc][jt], acc[jt][at], 0, 0, 0);
    }
#pragma unroll
    for (int at = 0; at < 4; ++at) {
        float4 bv = *(const float4*)&b2f[fb + at * 16 + q * 4];
        float s0 = 0.f, s1 = 0.f, s2 = 0.f, s3 = 0.f;
#pragma unroll
        for (int jt = 0; jt < 3; ++jt) {
            int node = nb + jt * 16 + ln15;
            if (node < 81) {
                s0 += fmaxf(acc[jt][at][0] * inv21 + bv.x, 0.0f);
                s1 += fmaxf(acc[jt][at][1] * inv21 + bv.y, 0.0f);
                s2 += fmaxf(acc[jt][at][2] * inv21 + bv.z, 0.0f);
                s3 += fmaxf(acc[jt][at][3] * inv21 + bv.w, 0.0f);
            }
        }
#pragma unroll
        for (int off = 1; off < 16; off <<= 1) {   // reduce over ln15 within q-group
            s0 += __shfl_xor(s0, off);
            s1 += __shfl_xor(s1, off);
            s2 += __shfl_xor(s2, off);
            s3 += __shfl_xor(s3, off);
        }
        if (ln15 == 0) {
            float4 v = {s0, s1, s2, s3};
            *(float4*)&sPoolPart[(wave & 1) * 128 + fb + at * 16 + q * 4] = v;
        }
    }
    __syncthreads();
    if (tid < 128) sPool[tid] = (sPoolPart[tid] + sPoolPart[128 + tid]) / 81.0f;
    __syncthreads();

    // ---------- S5: four heads (104 outputs) ----------
    if (tid < 104) {
        float a = bhf[tid];
        const float4* wrow = (const float4*)(whf + tid * 128);
        const float4* sp4  = (const float4*)sPool;
#pragma unroll 8
        for (int i = 0; i < 32; ++i) {
            float4 wv = wrow[i];
            float4 pv = sp4[i];
            a += pv.x * wv.x + pv.y * wv.y + pv.z * wv.z + pv.w * wv.w;
        }
        int o = tid, oo; size_t off;
        if (o < 4)       { oo = o;      off = (size_t)g * 4 + oo; }
        else if (o < 85) { oo = o - 4;  off = (size_t)nB * 4  + (size_t)g * 81 + oo; }
        else if (o < 94) { oo = o - 85; off = (size_t)nB * 85 + (size_t)g * 9  + oo; }
        else             { oo = o - 94; off = (size_t)nB * 94 + (size_t)g * 10 + oo; }
        if (f32) ((float*)out)[off] = a;
        else     ((unsigned short*)out)[off] = f2b(a);
    }
}

extern "C" void kernel_launch(void* const* d_in, const int* in_sizes, int n_in,
                              void* d_out, int out_size, void* d_ws, size_t ws_size,
                              hipStream_t stream) {
    // setup_inputs order: x, edge_index, batch, W1, b1, W2, b2, Wa, ba, Wc, bc, Wn, bn, Wt, bt
    const void* x  = d_in[0];
    int nB = in_sizes[2] / 81;
    if (nB <= 0) return;

    char* ws = (char*)d_ws;
    hipLaunchKernelGGL(k_repack, dim3(170), dim3(256), 0, stream,
                       x, d_in[3], d_in[4], d_in[5], d_in[6],
                       d_in[7], d_in[8], d_in[9], d_in[10],
                       d_in[11], d_in[12], d_in[13], d_in[14], ws);
    hipLaunchKernelGGL(sudoku_gnn, dim3(nB), dim3(256), 0, stream,
                       x, (const char*)ws, d_out, nB);
}

// Round 5
// 144.362 us; speedup vs baseline: 1.8907x; 1.0222x over previous
//
#include <hip/hip_runtime.h>
#include <hip/hip_bf16.h>

// Two sudoku graphs per block (A/B interleaved between barriers for ILP).
// All matmuls bf16 MFMA. S = (A+I) symmetric, deg==21 -> norm = 1/21.
// Transposed-aggregation keeps every MFMA C-tile write as b64 per lane.
// LDS: per-graph 128x128-ushort buffer (t^T and h aliased) with XOR chunk
// swizzle -> bank-uniform accesses (no conflicts).
typedef __attribute__((ext_vector_type(8))) short bf16x8;
typedef __attribute__((ext_vector_type(4))) float f32x4;

__device__ __forceinline__ unsigned short f2b(float f) {
    __hip_bfloat16 h = __float2bfloat16(f);
    return __builtin_bit_cast(unsigned short, h);
}
__device__ __forceinline__ float b2f(unsigned short u) {
    unsigned v = ((unsigned)u) << 16;
    return __builtin_bit_cast(float, v);
}
__device__ __forceinline__ float ldf(const void* p, int idx, bool f32) {
    return f32 ? ((const float*)p)[idx] : b2f(((const unsigned short*)p)[idx]);
}
__device__ __forceinline__ unsigned short ldb(const void* p, int idx, bool f32) {
    return f32 ? f2b(((const float*)p)[idx]) : ((const unsigned short*)p)[idx];
}
// XOR chunk swizzle: 128-ushort rows, 8-ushort chunks -> bank-uniform
__device__ __forceinline__ int swz(int row, int col) {
    return row * 128 + (((col >> 3) ^ (row & 7)) << 3) + (col & 7);
}

// dtype sniff from a uniform 64B of x (fp32 mantissa ushorts -> wild exponents)
__device__ __forceinline__ bool sniff_f32(const void* x) {
    const unsigned* p = (const unsigned*)x;
    int wild = 0;
#pragma unroll
    for (int i = 0; i < 16; ++i) {
        unsigned e = (p[i] >> 7) & 0xFF;
        wild += (e != 0 && (e < 0x68 || e > 0x90)) ? 1 : 0;
    }
    return wild > 8;
}

// ---- ws layout (bytes) ----
#define WS_B1F    16        // 128 f32
#define WS_B2F    528       // 128 f32
#define WS_BHF    1040      // 104 f32
#define WS_W1R    1536      // 128*32 bf16   [f][k]
#define WS_W2R    9728      // 128*128 bf16  [f][k]
#define WS_SR     42496     // 18*64*8 bf16  [(mi*3+kc)*64+lane][j]
#define WS_WH     60928     // 104*128 f32   [o][f]

__global__ void k_repack(const void* __restrict__ x,
                         const void* __restrict__ W1, const void* __restrict__ b1,
                         const void* __restrict__ W2, const void* __restrict__ b2,
                         const void* __restrict__ Wa, const void* __restrict__ ba,
                         const void* __restrict__ Wc, const void* __restrict__ bc,
                         const void* __restrict__ Wn, const void* __restrict__ bn,
                         const void* __restrict__ Wt, const void* __restrict__ bt,
                         char* __restrict__ ws) {
    const bool f32 = sniff_f32(x);
    int idx = blockIdx.x * blockDim.x + threadIdx.x;
    if (idx < 4096) {                         // w1r [f][k]
        int f = idx >> 5, k = idx & 31;
        unsigned short v = (k < 10) ? ldb(W1, k * 128 + f, f32) : (unsigned short)0;
        ((unsigned short*)(ws + WS_W1R))[idx] = v;
        return;
    }
    idx -= 4096;
    if (idx < 16384) {                        // w2r [f][k]
        int f = idx >> 7, k = idx & 127;
        ((unsigned short*)(ws + WS_W2R))[idx] = ldb(W2, k * 128 + f, f32);
        return;
    }
    idx -= 16384;
    if (idx < 9216) {                         // S fragments
        int fi = idx >> 9, rem = idx & 511;
        int lane = rem >> 3, j = rem & 7;
        int mi = fi / 3, kc = fi - mi * 3;
        int node = mi * 16 + (lane & 15);
        int cell = kc * 32 + ((lane >> 4) << 3) + j;
        bool adj = false;
        if (node < 81 && cell < 81) {
            int ni = node / 9, nj = node % 9;
            int ci = cell / 9, cj = cell % 9;
            adj = (ni == ci) || (nj == cj) ||
                  ((ni / 3 == ci / 3) && (nj / 3 == cj / 3));
        }
        ((unsigned short*)(ws + WS_SR))[idx] = adj ? (unsigned short)0x3F80 : (unsigned short)0;
        return;
    }
    idx -= 9216;
    if (idx < 13312) {                        // head weights (f32) [o][f]
        int o = idx >> 7, f = idx & 127;
        const void* W; int oo, dim;
        if (o < 4)       { W = Wa; oo = o;      dim = 4;  }
        else if (o < 85) { W = Wc; oo = o - 4;  dim = 81; }
        else if (o < 94) { W = Wn; oo = o - 85; dim = 9;  }
        else             { W = Wt; oo = o - 94; dim = 10; }
        ((float*)(ws + WS_WH))[idx] = ldf(W, f * dim + oo, f32);
        return;
    }
    idx -= 13312;
    if (idx < 360) {                          // biases
        float v;
        if (idx < 128)      v = ldf(b1, idx, f32);
        else if (idx < 256) v = ldf(b2, idx - 128, f32);
        else {
            int o = idx - 256;
            if (o < 4)       v = ldf(ba, o, f32);
            else if (o < 85) v = ldf(bc, o - 4, f32);
            else if (o < 94) v = ldf(bn, o - 85, f32);
            else             v = ldf(bt, o - 94, f32);
        }
        if (idx < 128)      ((float*)(ws + WS_B1F))[idx] = v;
        else if (idx < 256) ((float*)(ws + WS_B2F))[idx - 128] = v;
        else                ((float*)(ws + WS_BHF))[idx - 256] = v;
    }
}

__global__ __launch_bounds__(256, 2) void sudoku_gnn(
    const void* __restrict__ x, const char* __restrict__ ws,
    void* __restrict__ out, int nB)
{
    __shared__ __attribute__((aligned(16))) unsigned short sA[16384]; // graph A t^T/h
    __shared__ __attribute__((aligned(16))) unsigned short sB[16384]; // graph B t^T/h
    __shared__ __attribute__((aligned(16))) unsigned int   xs2[1632]; // raw x stage (2 graphs)
    __shared__ float sPoolPart[2][256];
    __shared__ float sPool[2][128];

    const bool f32 = sniff_f32(x);
    const unsigned short* w1r = (const unsigned short*)(ws + WS_W1R);
    const unsigned short* w2r = (const unsigned short*)(ws + WS_W2R);
    const unsigned short* sr  = (const unsigned short*)(ws + WS_SR);
    const float* b1f = (const float*)(ws + WS_B1F);
    const float* b2f = (const float*)(ws + WS_B2F);
    const float* bhf = (const float*)(ws + WS_BHF);
    const float* whf = (const float*)(ws + WS_WH);

    const int tid  = threadIdx.x;
    const int wave = tid >> 6;
    const int lane = tid & 63;
    const int ln15 = lane & 15;
    const int q    = lane >> 4;
    const int k0   = q * 8;
    const int mtb  = (wave & 1) * 3;      // node-half tiles
    const int nb   = (wave & 1) * 48;
    const int fb   = (wave >> 1) * 64;    // feature half
    const int g0   = blockIdx.x * 2;
    const int g1   = g0 + 1;
    const bool hasB = (g1 < nB);
    const float inv21 = 1.0f / 21.0f;
    unsigned short* const buf[2] = {sA, sB};

    // ---- stage raw x for both graphs (contiguous, coalesced) ----
    {
        const int words = f32 ? 810 : 405;             // per graph
        const int tot = words * (hasB ? 2 : 1);
        const unsigned int* src = (const unsigned int*)x + (size_t)g0 * words;
        for (int i = tid; i < tot; i += 256) xs2[i] = src[i];
    }

    // ---- persistent S fragments (B-operand; symmetric S) ----
    bf16x8 sfr[3][3];
#pragma unroll
    for (int kc = 0; kc < 3; ++kc)
#pragma unroll
        for (int jt = 0; jt < 3; ++jt)
            sfr[kc][jt] = *(const bf16x8*)&sr[(((mtb + jt) * 3 + kc) * 64 + lane) * 8];
    bf16x8 w1f[4];
#pragma unroll
    for (int nt = 0; nt < 4; ++nt)
        w1f[nt] = *(const bf16x8*)&w1r[(fb + nt * 16 + ln15) * 32 + k0];

    __syncthreads();   // (1) xs2 ready

    // ---- x A-frags ----
    bf16x8 xf[2][3];
#pragma unroll
    for (int gg = 0; gg < 2; ++gg)
#pragma unroll
        for (int mt = 0; mt < 3; ++mt) {
            int node = (mtb + mt) * 16 + ln15;
            bf16x8 v = {0, 0, 0, 0, 0, 0, 0, 0};
            if (node < 81) {
                int base = gg * 810 + node * 10;
                if (q == 0) {
#pragma unroll
                    for (int jj = 0; jj < 8; ++jj)
                        v[jj] = (short)(f32 ? f2b(((const float*)xs2)[base + jj])
                                            : ((const unsigned short*)xs2)[base + jj]);
                } else if (q == 1) {
#pragma unroll
                    for (int jj = 0; jj < 2; ++jj)
                        v[jj] = (short)(f32 ? f2b(((const float*)xs2)[base + 8 + jj])
                                            : ((const unsigned short*)xs2)[base + 8 + jj]);
                }
            }
            xf[gg][mt] = v;
        }

    const f32x4 z4 = {0.f, 0.f, 0.f, 0.f};
    f32x4 acc[2][3][4];

    // ---------- S1: t = x @ W1 ; write t^T[f][cell] ----------
#pragma unroll
    for (int gg = 0; gg < 2; ++gg)
#pragma unroll
        for (int mt = 0; mt < 3; ++mt)
#pragma unroll
            for (int nt = 0; nt < 4; ++nt)
                acc[gg][mt][nt] = __builtin_amdgcn_mfma_f32_16x16x32_bf16(xf[gg][mt], w1f[nt], z4, 0, 0, 0);
#pragma unroll
    for (int gg = 0; gg < 2; ++gg)
#pragma unroll
        for (int mt = 0; mt < 3; ++mt)
#pragma unroll
            for (int nt = 0; nt < 4; ++nt) {
                int f = fb + nt * 16 + ln15;
                int nodeb = (mtb + mt) * 16 + q * 4;
                unsigned lo = (unsigned)f2b(acc[gg][mt][nt][0]) | ((unsigned)f2b(acc[gg][mt][nt][1]) << 16);
                unsigned hi = (unsigned)f2b(acc[gg][mt][nt][2]) | ((unsigned)f2b(acc[gg][mt][nt][3]) << 16);
                *(uint2*)&buf[gg][swz(f, nodeb)] = make_uint2(lo, hi);
            }
    __syncthreads();   // (2)

    // ---------- S2: h^T = t^T @ S ; write h[node][f] ----------
#pragma unroll
    for (int gg = 0; gg < 2; ++gg)
#pragma unroll
        for (int a = 0; a < 3; ++a)
#pragma unroll
            for (int b = 0; b < 4; ++b) acc[gg][a][b] = z4;
#pragma unroll
    for (int kc = 0; kc < 3; ++kc) {
        bf16x8 a4[2][4];
#pragma unroll
        for (int gg = 0; gg < 2; ++gg)
#pragma unroll
            for (int at = 0; at < 4; ++at)
                a4[gg][at] = *(const bf16x8*)&buf[gg][swz(fb + at * 16 + ln15, kc * 32 + k0)];
#pragma unroll
        for (int gg = 0; gg < 2; ++gg)
#pragma unroll
            for (int at = 0; at < 4; ++at)
#pragma unroll
                for (int jt = 0; jt < 3; ++jt)
                    acc[gg][jt][at] = __builtin_amdgcn_mfma_f32_16x16x32_bf16(a4[gg][at], sfr[kc][jt], acc[gg][jt][at], 0, 0, 0);
    }
    __syncthreads();   // (3) t^T reads complete before aliased h writes
#pragma unroll
    for (int gg = 0; gg < 2; ++gg)
#pragma unroll
        for (int at = 0; at < 4; ++at) {
            float4 bv = *(const float4*)&b1f[fb + at * 16 + q * 4];
#pragma unroll
            for (int jt = 0; jt < 3; ++jt) {
                int node = nb + jt * 16 + ln15;
                float v0 = fmaxf(acc[gg][jt][at][0] * inv21 + bv.x, 0.0f);
                float v1 = fmaxf(acc[gg][jt][at][1] * inv21 + bv.y, 0.0f);
                float v2 = fmaxf(acc[gg][jt][at][2] * inv21 + bv.z, 0.0f);
                float v3 = fmaxf(acc[gg][jt][at][3] * inv21 + bv.w, 0.0f);
                unsigned lo = (unsigned)f2b(v0) | ((unsigned)f2b(v1) << 16);
                unsigned hi = (unsigned)f2b(v2) | ((unsigned)f2b(v3) << 16);
                *(uint2*)&buf[gg][swz(node, fb + at * 16 + q * 4)] = make_uint2(lo, hi);
            }
        }
    __syncthreads();   // (4)

    // ---------- S3: t2 = h @ W2 ; write t2^T[f][cell] ----------
#pragma unroll
    for (int gg = 0; gg < 2; ++gg)
#pragma unroll
        for (int a = 0; a < 3; ++a)
#pragma unroll
            for (int b = 0; b < 4; ++b) acc[gg][a][b] = z4;
#pragma unroll
    for (int kc = 0; kc < 4; ++kc) {
        bf16x8 w2f[4];
#pragma unroll
        for (int nt = 0; nt < 4; ++nt)
            w2f[nt] = *(const bf16x8*)&w2r[(fb + nt * 16 + ln15) * 128 + kc * 32 + k0];
        bf16x8 a3[2][3];
#pragma unroll
        for (int gg = 0; gg < 2; ++gg)
#pragma unroll
            for (int mt = 0; mt < 3; ++mt)
                a3[gg][mt] = *(const bf16x8*)&buf[gg][swz((mtb + mt) * 16 + ln15, kc * 32 + k0)];
#pragma unroll
        for (int gg = 0; gg < 2; ++gg)
#pragma unroll
            for (int mt = 0; mt < 3; ++mt)
#pragma unroll
                for (int nt = 0; nt < 4; ++nt)
                    acc[gg][mt][nt] = __builtin_amdgcn_mfma_f32_16x16x32_bf16(a3[gg][mt], w2f[nt], acc[gg][mt][nt], 0, 0, 0);
    }
    __syncthreads();   // (5) h reads complete before aliased t^T writes
#pragma unroll
    for (int gg = 0; gg < 2; ++gg)
#pragma unroll
        for (int mt = 0; mt < 3; ++mt)
#pragma unroll
            for (int nt = 0; nt < 4; ++nt) {
                int f = fb + nt * 16 + ln15;
                int nodeb = (mtb + mt) * 16 + q * 4;
                unsigned lo = (unsigned)f2b(acc[gg][mt][nt][0]) | ((unsigned)f2b(acc[gg][mt][nt][1]) << 16);
                unsigned hi = (unsigned)f2b(acc[gg][mt][nt][2]) | ((unsigned)f2b(acc[gg][mt][nt][3]) << 16);
                *(uint2*)&buf[gg][swz(f, nodeb)] = make_uint2(lo, hi);
            }
    __syncthreads();   // (6)

    // ---------- S4: h2^T = t2^T @ S ; relu(+b2) fused mean-pool ----------
#pragma unroll
    for (int gg = 0; gg < 2; ++gg)
#pragma unroll
        for (int a = 0; a < 3; ++a)
#pragma unroll
            for (int b = 0; b < 4; ++b) acc[gg][a][b] = z4;
#pragma unroll
    for (int kc = 0; kc < 3; ++kc) {
        bf16x8 a4[2][4];
#pragma unroll
        for (int gg = 0; gg < 2; ++gg)
#pragma unroll
            for (int at = 0; at < 4; ++at)
                a4[gg][at] = *(const bf16x8*)&buf[gg][swz(fb + at * 16 + ln15, kc * 32 + k0)];
#pragma unroll
        for (int gg = 0; gg < 2; ++gg)
#pragma unroll
            for (int at = 0; at < 4; ++at)
#pragma unroll
                for (int jt = 0; jt < 3; ++jt)
                    acc[gg][jt][at] = __builtin_amdgcn_mfma_f32_16x16x32_bf16(a4[gg][at], sfr[kc][jt], acc[gg][jt][at], 0, 0, 0);
    }
#pragma unroll
    for (int gg = 0; gg < 2; ++gg)
#pragma unroll
        for (int at = 0; at < 4; ++at) {
            float4 bv = *(const float4*)&b2f[fb + at * 16 + q * 4];
            float s0 = 0.f, s1 = 0.f, s2 = 0.f, s3 = 0.f;
#pragma unroll
            for (int jt = 0; jt < 3; ++jt) {
                int node = nb + jt * 16 + ln15;
                if (node < 81) {
                    s0 += fmaxf(acc[gg][jt][at][0] * inv21 + bv.x, 0.0f);
                    s1 += fmaxf(acc[gg][jt][at][1] * inv21 + bv.y, 0.0f);
                    s2 += fmaxf(acc[gg][jt][at][2] * inv21 + bv.z, 0.0f);
                    s3 += fmaxf(acc[gg][jt][at][3] * inv21 + bv.w, 0.0f);
                }
            }
#pragma unroll
            for (int off = 1; off < 16; off <<= 1) {
                s0 += __shfl_xor(s0, off);
                s1 += __shfl_xor(s1, off);
                s2 += __shfl_xor(s2, off);
                s3 += __shfl_xor(s3, off);
            }
            if (ln15 == 0) {
                float4 v = {s0, s1, s2, s3};
                *(float4*)&sPoolPart[gg][(wave & 1) * 128 + fb + at * 16 + q * 4] = v;
            }
        }
    __syncthreads();   // (7)
    {
        int gg = tid >> 7;            // 0: A, 1: B
        int f  = tid & 127;
        sPool[gg][f] = (sPoolPart[gg][f] + sPoolPart[gg][128 + f]) / 81.0f;
    }
    __syncthreads();   // (8)

    // ---------- S5: heads (104 outputs per graph; A on tids 0.., B on 128..) ----------
    {
        int gg = tid >> 7;
        int o  = tid & 127;
        int g  = gg ? g1 : g0;
        if (o < 104 && (gg == 0 || hasB)) {
            float a = bhf[o];
            const float4* wrow = (const float4*)(whf + o * 128);
            const float4* sp4  = (const float4*)sPool[gg];
#pragma unroll 8
            for (int i = 0; i < 32; ++i) {
                float4 wv = wrow[i];
                float4 pv = sp4[i];
                a += pv.x * wv.x + pv.y * wv.y + pv.z * wv.z + pv.w * wv.w;
            }
            int oo; size_t off;
            if (o < 4)       { oo = o;      off = (size_t)g * 4 + oo; }
            else if (o < 85) { oo = o - 4;  off = (size_t)nB * 4  + (size_t)g * 81 + oo; }
            else if (o < 94) { oo = o - 85; off = (size_t)nB * 85 + (size_t)g * 9  + oo; }
            else             { oo = o - 94; off = (size_t)nB * 94 + (size_t)g * 10 + oo; }
            if (f32) ((float*)out)[off] = a;
            else     ((unsigned short*)out)[off] = f2b(a);
        }
    }
}

extern "C" void kernel_launch(void* const* d_in, const int* in_sizes, int n_in,
                              void* d_out, int out_size, void* d_ws, size_t ws_size,
                              hipStream_t stream) {
    // setup_inputs order: x, edge_index, batch, W1, b1, W2, b2, Wa, ba, Wc, bc, Wn, bn, Wt, bt
    const void* x  = d_in[0];
    int nB = in_sizes[2] / 81;
    if (nB <= 0) return;

    char* ws = (char*)d_ws;
    hipLaunchKernelGGL(k_repack, dim3(170), dim3(256), 0, stream,
                       x, d_in[3], d_in[4], d_in[5], d_in[6],
                       d_in[7], d_in[8], d_in[9], d_in[10],
                       d_in[11], d_in[12], d_in[13], d_in[14], ws);
    hipLaunchKernelGGL(sudoku_gnn, dim3((nB + 1) / 2), dim3(256), 0, stream,
                       x, (const char*)ws, d_out, nB);
}